// Round 1
// baseline (156.417 us; speedup 1.0000x reference)
//
#include <hip/hip_runtime.h>
#include <cstdint>
#include <cstddef>

// ---------------------------------------------------------------------------
// y[b,o] = sum_{i,j<257} x1[b,i] x1[b,j] W[o, i*257+j] + bias[o],  x1=[1,x]
// Decomposition:
//   main : ii in [0,257), j in [0,256)   -> Wp[o][ii][j] = W[o, ii*257+j]
//   pseudo slice ii=257, jj in [0,256)   -> Wp[o][257][jj] = W[o, jj*257+256]
//                                           (scalar = x1[256])
//   corner (256,256) + bias             -> init_out kernel (exact fp32)
// GEMM: M=2048 (batch), N=256 (outputs), 258 slices x 8 K-steps of 32.
// ---------------------------------------------------------------------------

typedef _Float16 half8 __attribute__((ext_vector_type(8)));
typedef float    f32x4 __attribute__((ext_vector_type(4)));

#define KSPLIT 16

#define WAITVM(N) asm volatile("s_waitcnt vmcnt(" #N ")" ::: "memory")
#define WAITLGKM  asm volatile("s_waitcnt lgkmcnt(0)" ::: "memory")

__device__ __forceinline__ void gload_lds16(const void* g, void* lds) {
  __builtin_amdgcn_global_load_lds(
      (const __attribute__((address_space(1))) uint32_t*)g,
      (__attribute__((address_space(3))) uint32_t*)lds, 16, 0, 0);
}

// ---- stage 1: W [256][66049] f32 -> Wp [o][ii(258)][j(256)] f16 -------------
__global__ void conv_w_k(const float* __restrict__ W, _Float16* __restrict__ Wp) {
  int t   = blockIdx.x * 256 + threadIdx.x;   // total 256*258*32 = 2,113,536
  int j8  = t & 31;
  int rem = t >> 5;
  int ii  = rem % 258;
  int o   = rem / 258;
  float v[8];
  if (ii < 257) {
    const float* src = W + (size_t)o * 66049 + ii * 257 + j8 * 8;
#pragma unroll
    for (int u = 0; u < 8; ++u) v[u] = src[u];
  } else {
    const float* src = W + (size_t)o * 66049 + 256;
#pragma unroll
    for (int u = 0; u < 8; ++u) v[u] = src[(size_t)(j8 * 8 + u) * 257];
  }
  half8 h;
#pragma unroll
  for (int u = 0; u < 8; ++u) h[u] = (_Float16)v[u];
  *(half8*)(Wp + ((size_t)o * 258 + ii) * 256 + j8 * 8) = h;
}

// ---- stage 1b: x [2048][256] f32 -> X1g [2048][264] f16 (x1 padded) ---------
__global__ void conv_x1_k(const float* __restrict__ x, _Float16* __restrict__ X1g) {
  int t  = blockIdx.x * 256 + threadIdx.x;    // total 2048*33 = 67584
  int j8 = t % 33;
  int b  = t / 33;
  half8 h;
#pragma unroll
  for (int u = 0; u < 8; ++u) {
    int jj = j8 * 8 + u;
    float v = (jj == 0) ? 1.0f : (jj <= 256 ? x[(size_t)b * 256 + (jj - 1)] : 0.0f);
    h[u] = (_Float16)v;
  }
  *(half8*)(X1g + (size_t)b * 264 + j8 * 8) = h;
}

// ---- init: Y = bias + x1[256]^2 * W[o,66048]  (exact fp32 terms) ------------
__global__ void init_out_k(const float* __restrict__ x, const float* __restrict__ W,
                           const float* __restrict__ bias, float* __restrict__ Y) {
  int o = threadIdx.x;
  int b = blockIdx.x;
  float xl = x[(size_t)b * 256 + 255];
  float w  = W[(size_t)o * 66049 + 66048];
  Y[(size_t)b * 256 + o] = bias[o] + xl * xl * w;
}

// ---- main GEMM: virtual A = x1[b,ii] * x1[b,j], B = Wp slice ----------------
__global__ __launch_bounds__(512, 2)
void gemm_k(const _Float16* __restrict__ Wp, const _Float16* __restrict__ X1g,
            float* __restrict__ Y) {
  __shared__ __align__(16) _Float16 x1t[128 * 264];   // 67584 B
  __shared__ __align__(16) _Float16 wbuf[3 * 8192];   // 3 x 16 KB K-step tiles

  const int bid = blockIdx.x;
  const int s   = bid & (KSPLIT - 1);   // split id -> XCD = bid%8 pins slice to L2
  const int mt  = bid >> 4;             // m-tile
  const int nii = 16 + (s < 2 ? 1 : 0); // 258 = 2*17 + 14*16
  const int ii0 = s * 16 + (s < 2 ? s : 2);

  const int tid = threadIdx.x;
  const int l   = tid & 63;
  const int w   = tid >> 6;   // wave 0..7
  const int wm  = w >> 2;     // 0..1
  const int wn  = w & 3;      // 0..3
  const int ln  = l & 15;
  const int ks  = l >> 4;

  // ---- stage X1 tile (lane-linear, 4224 x 16B) ----
  const _Float16* xsrc = X1g + (size_t)mt * (128 * 264);
  for (int it = 0; it < 9; ++it) {
    int idx = it * 512 + tid;
    if (idx < 4224)
      gload_lds16(xsrc + idx * 8, (char*)x1t + (it * 512 + w * 64) * 16);
  }
  WAITVM(0);
  __builtin_amdgcn_s_barrier();

  // ---- i-invariant A base fragments: x1[m, j-chunk] in registers ----
  half8 base[4][8];
#pragma unroll
  for (int mf = 0; mf < 4; ++mf)
#pragma unroll
    for (int jc = 0; jc < 8; ++jc)
      base[mf][jc] = *(const half8*)(x1t + (wm * 64 + mf * 16 + ln) * 264 + jc * 32 + ks * 8);

  f32x4 acc[4][4];
#pragma unroll
  for (int mf = 0; mf < 4; ++mf)
#pragma unroll
    for (int nf = 0; nf < 4; ++nf) acc[mf][nf] = (f32x4){0.f, 0.f, 0.f, 0.f};

  // W staging: fragment-ordered gather; LDS dest lane-linear (conflict-free)
  auto stage = [&](int buf, int ii, int jc) {
#pragma unroll
    for (int t2 = 0; t2 < 2; ++t2) {
      int f = t2 * 8 + w;     // n-fragment 0..15
      const _Float16* g = Wp + ((size_t)(f * 16 + ln) * 258 + ii) * 256 + jc * 32 + ks * 8;
      gload_lds16(g, (char*)wbuf + buf * 16384 + f * 1024);
    }
  };

  const int nsteps = nii * 8;
  stage(0, ii0, 0);
  stage(1, ii0, 1);
  WAITVM(2);
  __builtin_amdgcn_s_barrier();

  int bc = 0;
  for (int iio = 0; iio < nii; ++iio) {
    const int ii = ii0 + iio;
    const int si = (ii < 257) ? ii : 256;   // scalar index: x1[min(ii,256)]
    half8 s8[4];
#pragma unroll
    for (int mf = 0; mf < 4; ++mf) {
      _Float16 sv = x1t[(wm * 64 + mf * 16 + ln) * 264 + si];
      s8[mf] = (half8){sv, sv, sv, sv, sv, sv, sv, sv};
    }
#pragma unroll
    for (int jc = 0; jc < 8; ++jc) {
      const int st  = iio * 8 + jc;
      const int st2 = st + 2;
      int bs = bc + 2; if (bs >= 3) bs -= 3;
      const bool more = (st2 < nsteps);
      if (more) stage(bs, ii0 + (st2 >> 3), st2 & 7);

      half8 af[4];
#pragma unroll
      for (int mf = 0; mf < 4; ++mf) af[mf] = base[mf][jc] * s8[mf];  // v_pk_mul_f16

      const _Float16* wb = wbuf + bc * 8192 + (wn * 4) * 512 + l * 8;
#pragma unroll
      for (int nf = 0; nf < 4; ++nf) {
        half8 bf = *(const half8*)(wb + nf * 512);
#pragma unroll
        for (int mf = 0; mf < 4; ++mf)
          acc[mf][nf] = __builtin_amdgcn_mfma_f32_16x16x32_f16(af[mf], bf, acc[mf][nf], 0, 0, 0);
      }
      if (more) { WAITVM(2); } else { WAITVM(0); }
      WAITLGKM;
      __builtin_amdgcn_s_barrier();
      bc = bc + 1; if (bc == 3) bc = 0;
    }
  }

  // ---- epilogue: atomic accumulate (C/D layout: col=l&15, row=ks*4+r) ----
  float* yb = Y + (size_t)(mt * 128 + wm * 64) * 256 + wn * 64;
  const int r0 = ks * 4;
#pragma unroll
  for (int mf = 0; mf < 4; ++mf)
#pragma unroll
    for (int nf = 0; nf < 4; ++nf)
#pragma unroll
      for (int r = 0; r < 4; ++r)
        unsafeAtomicAdd(&yb[(size_t)(mf * 16 + r0 + r) * 256 + nf * 16 + ln],
                        acc[mf][nf][r]);
}

// ---- emergency fallback if ws too small (correct, slow) ---------------------
__global__ void fb_k(const float* __restrict__ x, const float* __restrict__ W,
                     const float* __restrict__ bias, float* __restrict__ Y) {
  __shared__ float x1[257];
  int b = blockIdx.x, o = threadIdx.x;
  x1[o + 1] = x[(size_t)b * 256 + o];
  if (o == 0) x1[0] = 1.0f;
  __syncthreads();
  const float* Wr = W + (size_t)o * 66049;
  float acc = bias[o];
  for (int i = 0; i < 257; ++i) {
    const float* wr = Wr + (size_t)i * 257;
    float p = 0.f;
    for (int j = 0; j < 257; ++j) p = fmaf(x1[j], wr[j], p);
    acc = fmaf(x1[i], p, acc);
  }
  Y[(size_t)b * 256 + o] = acc;
}

extern "C" void kernel_launch(void* const* d_in, const int* in_sizes, int n_in,
                              void* d_out, int out_size, void* d_ws, size_t ws_size,
                              hipStream_t stream) {
  const float* x = (const float*)d_in[0];
  const float* W = (const float*)d_in[1];
  const float* b = (const float*)d_in[2];
  float* y = (float*)d_out;

  const size_t WPB = (size_t)256 * 258 * 256 * 2;  // 33,816,576 B
  const size_t X1B = (size_t)2048 * 264 * 2;       //  1,081,344 B
  if (ws_size < WPB + X1B) {
    fb_k<<<2048, 256, 0, stream>>>(x, W, b, y);
    return;
  }
  _Float16* Wp  = (_Float16*)d_ws;
  _Float16* X1g = (_Float16*)((char*)d_ws + WPB);

  conv_w_k<<<8256, 256, 0, stream>>>(W, Wp);
  conv_x1_k<<<264, 256, 0, stream>>>(x, X1g);
  init_out_k<<<2048, 256, 0, stream>>>(x, W, b, y);
  gemm_k<<<256, 512, 0, stream>>>(Wp, X1g, y);
}

// Round 2
// 142.871 us; speedup vs baseline: 1.0948x; 1.0948x over previous
//
#include <hip/hip_runtime.h>
#include <cstdint>
#include <cstddef>

// ---------------------------------------------------------------------------
// y[b,o] = sum_{i,j<257} x1[b,i] x1[b,j] W[o, i*257+j] + bias[o],  x1=[1,x]
// Decomposition:
//   main : ii in [0,257), j in [0,256)   -> Wp[o][ii][j] = W[o, ii*257+j]
//   pseudo slice ii=257, jj in [0,256)   -> Wp[o][257][jj] = W[o, jj*257+256]
//                                           (scalar = x1[256])
//   corner (256,256) + bias             -> init_out kernel (exact fp32)
// GEMM: M=2048 (batch), N=256 (outputs), 258 slices x 8 K-steps of 32.
// Round 2: x1 j-fragments register-resident (no x1t LDS), 4-buffer W pipeline
// with counted vmcnt(4) (prefetch depth 3), tiny scal LDS table.
// ---------------------------------------------------------------------------

typedef _Float16 half8 __attribute__((ext_vector_type(8)));
typedef float    f32x4 __attribute__((ext_vector_type(4)));

#define KSPLIT 16

#define WAITVM(N) asm volatile("s_waitcnt vmcnt(" #N ")" ::: "memory")
#define WAITLGKM  asm volatile("s_waitcnt lgkmcnt(0)" ::: "memory")

__device__ __forceinline__ void gload_lds16(const void* g, void* lds) {
  __builtin_amdgcn_global_load_lds(
      (const __attribute__((address_space(1))) uint32_t*)g,
      (__attribute__((address_space(3))) uint32_t*)lds, 16, 0, 0);
}

// ---- stage 1: W [256][66049] f32 -> Wp [o][ii(258)][j(256)] f16 -------------
__global__ void conv_w_k(const float* __restrict__ W, _Float16* __restrict__ Wp) {
  int t   = blockIdx.x * 256 + threadIdx.x;   // total 256*258*32 = 2,113,536
  int j8  = t & 31;
  int rem = t >> 5;
  int ii  = rem % 258;
  int o   = rem / 258;
  float v[8];
  if (ii < 257) {
    const float* src = W + (size_t)o * 66049 + ii * 257 + j8 * 8;
#pragma unroll
    for (int u = 0; u < 8; ++u) v[u] = src[u];
  } else {
    const float* src = W + (size_t)o * 66049 + 256;
#pragma unroll
    for (int u = 0; u < 8; ++u) v[u] = src[(size_t)(j8 * 8 + u) * 257];
  }
  half8 h;
#pragma unroll
  for (int u = 0; u < 8; ++u) h[u] = (_Float16)v[u];
  *(half8*)(Wp + ((size_t)o * 258 + ii) * 256 + j8 * 8) = h;
}

// ---- stage 1b: x [2048][256] f32 -> X1g [2048][264] f16 (x1 padded) ---------
__global__ void conv_x1_k(const float* __restrict__ x, _Float16* __restrict__ X1g) {
  int t  = blockIdx.x * 256 + threadIdx.x;    // total 2048*33 = 67584
  int j8 = t % 33;
  int b  = t / 33;
  half8 h;
#pragma unroll
  for (int u = 0; u < 8; ++u) {
    int jj = j8 * 8 + u;
    float v = (jj == 0) ? 1.0f : (jj <= 256 ? x[(size_t)b * 256 + (jj - 1)] : 0.0f);
    h[u] = (_Float16)v;
  }
  *(half8*)(X1g + (size_t)b * 264 + j8 * 8) = h;
}

// ---- init: Y = bias + x1[256]^2 * W[o,66048]  (exact fp32 terms) ------------
__global__ void init_out_k(const float* __restrict__ x, const float* __restrict__ W,
                           const float* __restrict__ bias, float* __restrict__ Y) {
  int o = threadIdx.x;
  int b = blockIdx.x;
  float xl = x[(size_t)b * 256 + 255];
  float w  = W[(size_t)o * 66049 + 66048];
  Y[(size_t)b * 256 + o] = bias[o] + xl * xl * w;
}

// ---- main GEMM: virtual A = x1[b,ii] * x1[b,j], B = Wp slice ----------------
__global__ __launch_bounds__(512, 2)
void gemm_k(const _Float16* __restrict__ Wp, const _Float16* __restrict__ X1g,
            float* __restrict__ Y) {
  __shared__ __align__(16) _Float16 wbuf[4 * 8192];   // 4 x 16 KB K-step tiles
  __shared__ _Float16 scal[17 * 128];                 // x1[m, ii] per slice

  const int bid = blockIdx.x;
  const int s   = bid & (KSPLIT - 1);   // split id -> XCD = bid%8 pins slice to L2
  const int mt  = bid >> 4;             // m-tile
  const int nii = 16 + (s < 2 ? 1 : 0); // 258 = 2*17 + 14*16
  const int ii0 = s * 16 + (s < 2 ? s : 2);

  const int tid = threadIdx.x;
  const int l   = tid & 63;
  const int w   = tid >> 6;   // wave 0..7
  const int wm  = w >> 2;     // 0..1
  const int wn  = w & 3;      // 0..3
  const int ln  = l & 15;
  const int ks  = l >> 4;

  // ---- scal table: scal[k][m] = x1[mt*128+m, min(ii0+k,256)] ----
  for (int t = tid; t < nii * 128; t += 512) {
    int k = t >> 7, m = t & 127;
    int ii = ii0 + k; if (ii > 256) ii = 256;
    scal[k * 128 + m] = X1g[(size_t)(mt * 128 + m) * 264 + ii];
  }

  // ---- i-invariant A base fragments: x1[row, j-chunk] -> 128 VGPRs ----
  half8 base[4][8];
  {
    const _Float16* xr = X1g + (size_t)(mt * 128 + wm * 64 + ln) * 264 + ks * 8;
#pragma unroll
    for (int mf = 0; mf < 4; ++mf)
#pragma unroll
      for (int jc = 0; jc < 8; ++jc)
        base[mf][jc] = *(const half8*)(xr + (size_t)mf * (16 * 264) + jc * 32);
  }

  f32x4 acc[4][4];
#pragma unroll
  for (int mf = 0; mf < 4; ++mf)
#pragma unroll
    for (int nf = 0; nf < 4; ++nf) acc[mf][nf] = (f32x4){0.f, 0.f, 0.f, 0.f};

  // W staging: fragment-ordered gather; LDS dest lane-linear (conflict-free)
  auto stage = [&](int buf, int ii, int jc) {
#pragma unroll
    for (int t2 = 0; t2 < 2; ++t2) {
      int f = t2 * 8 + w;     // n-fragment 0..15
      const _Float16* g = Wp + ((size_t)(f * 16 + ln) * 258 + ii) * 256 + jc * 32 + ks * 8;
      gload_lds16(g, (char*)wbuf + buf * 16384 + f * 1024);
    }
  };

  const int nsteps = nii * 8;
  stage(0, ii0, 0);
  stage(1, ii0, 1);
  stage(2, ii0, 2);
  WAITVM(4);      // buffer 0 ready (own loads for step 0 done)
  WAITLGKM;       // scal writes done
  __builtin_amdgcn_s_barrier();

  for (int iio = 0; iio < nii; ++iio) {
    half8 s8[4];
#pragma unroll
    for (int mf = 0; mf < 4; ++mf) {
      _Float16 sv = scal[iio * 128 + wm * 64 + mf * 16 + ln];
      s8[mf] = (half8){sv, sv, sv, sv, sv, sv, sv, sv};
    }
#pragma unroll
    for (int jc = 0; jc < 8; ++jc) {
      const int st  = iio * 8 + jc;
      const int st3 = st + 3;
      if (st3 < nsteps) stage(st3 & 3, ii0 + (st3 >> 3), st3 & 7);

      half8 af[4];
#pragma unroll
      for (int mf = 0; mf < 4; ++mf) af[mf] = base[mf][jc] * s8[mf];  // v_pk_mul_f16

      const _Float16* wb = wbuf + (st & 3) * 8192 + (wn * 4) * 512 + l * 8;
#pragma unroll
      for (int nf = 0; nf < 4; ++nf) {
        half8 bf = *(const half8*)(wb + nf * 512);
#pragma unroll
        for (int mf = 0; mf < 4; ++mf)
          acc[mf][nf] = __builtin_amdgcn_mfma_f32_16x16x32_f16(af[mf], bf, acc[mf][nf], 0, 0, 0);
      }
      // counted waits: need stage for step st+1 complete before next iter
      const int rem = nsteps - 1 - st;   // stages still outstanding beyond st+1's need
      if (rem >= 3)      { WAITVM(4); }
      else if (rem == 2) { WAITVM(2); }
      else if (rem == 1) { WAITVM(0); }
      WAITLGKM;
      __builtin_amdgcn_s_barrier();
    }
  }

  // ---- epilogue: atomic accumulate (C/D layout: col=l&15, row=ks*4+r) ----
  float* yb = Y + (size_t)(mt * 128 + wm * 64) * 256 + wn * 64;
  const int r0 = ks * 4;
#pragma unroll
  for (int mf = 0; mf < 4; ++mf)
#pragma unroll
    for (int nf = 0; nf < 4; ++nf)
#pragma unroll
      for (int r = 0; r < 4; ++r)
        unsafeAtomicAdd(&yb[(size_t)(mf * 16 + r0 + r) * 256 + nf * 16 + ln],
                        acc[mf][nf][r]);
}

// ---- emergency fallback if ws too small (correct, slow) ---------------------
__global__ void fb_k(const float* __restrict__ x, const float* __restrict__ W,
                     const float* __restrict__ bias, float* __restrict__ Y) {
  __shared__ float x1[257];
  int b = blockIdx.x, o = threadIdx.x;
  x1[o + 1] = x[(size_t)b * 256 + o];
  if (o == 0) x1[0] = 1.0f;
  __syncthreads();
  const float* Wr = W + (size_t)o * 66049;
  float acc = bias[o];
  for (int i = 0; i < 257; ++i) {
    const float* wr = Wr + (size_t)i * 257;
    float p = 0.f;
    for (int j = 0; j < 257; ++j) p = fmaf(x1[j], wr[j], p);
    acc = fmaf(x1[i], p, acc);
  }
  Y[(size_t)b * 256 + o] = acc;
}

extern "C" void kernel_launch(void* const* d_in, const int* in_sizes, int n_in,
                              void* d_out, int out_size, void* d_ws, size_t ws_size,
                              hipStream_t stream) {
  const float* x = (const float*)d_in[0];
  const float* W = (const float*)d_in[1];
  const float* b = (const float*)d_in[2];
  float* y = (float*)d_out;

  const size_t WPB = (size_t)256 * 258 * 256 * 2;  // 33,816,576 B
  const size_t X1B = (size_t)2048 * 264 * 2;       //  1,081,344 B
  if (ws_size < WPB + X1B) {
    fb_k<<<2048, 256, 0, stream>>>(x, W, b, y);
    return;
  }
  _Float16* Wp  = (_Float16*)d_ws;
  _Float16* X1g = (_Float16*)((char*)d_ws + WPB);

  conv_w_k<<<8256, 256, 0, stream>>>(W, Wp);
  conv_x1_k<<<264, 256, 0, stream>>>(x, X1g);
  init_out_k<<<2048, 256, 0, stream>>>(x, W, b, y);
  gemm_k<<<256, 512, 0, stream>>>(Wp, X1g, y);
}